// Round 21
// baseline (1802.903 us; speedup 1.0000x reference)
//
#include <hip/hip_runtime.h>
#include <hip/hip_cooperative_groups.h>
#include <limits.h>

namespace cg = cooperative_groups;

// Problem constants (fixed by the reference: LATTICE=(4096,4096), N_CLUSTERS=262144)
#define N_SITES   (4096 * 4096)      // 16,777,216
#define N_INT4    (N_SITES / 4)      // 4,194,304
#define N_LABELS  262144
#define NWORDS    (N_SITES / 32)     // 524,288 bitmap words
#define NSEENW    (N_LABELS / 32)    // 8,192 seen/flip bitmap words (32 KB)
#define WPC       256                // words per chunk
#define NCHUNKS   (NWORDS / WPC)     // 2048

// Atomic ledger (R20, kept): S=524K seed, passA spans 1.05M sites, passB rest.
#define SEED_TPB    256
#define SEED_BLOCKS 512
#define SEED_INT4   (SEED_BLOCKS * SEED_TPB)     // 131,072 int4 = 524,288 sites
#define ZERO_BLOCKS 512
#define A_END_INT4  (SEED_INT4 + 262144)         // 393,216 int4 = 1,572,864 sites

// Mega/flat geometry: 512 blocks x 1024 thr = 524,288 threads, 2 blocks/CU.
#define GRID  512
#define TPB   1024
#define TOT   (GRID * TPB)                       // 524,288 (== NWORDS)
#define FLAT_BLOCKS 512
#define FLAT_TPB    1024
#define FLAT_THREADS (FLAT_BLOCKS * FLAT_TPB)

typedef float f32x4 __attribute__((ext_vector_type(4)));

// ============ MEGA KERNEL: all 11 phases, grid.sync between them ============
__global__ void __launch_bounds__(TPB, 8)
k_mega(const int4* __restrict__ lab4, int* __restrict__ first_idx,
       unsigned* __restrict__ bitmap, unsigned* __restrict__ seen,
       unsigned* __restrict__ flipbits, int* __restrict__ chunkSums,
       int* __restrict__ wordPrefix, const float* __restrict__ coins,
       const float* __restrict__ spins, float* __restrict__ out) {
    cg::grid_group grid = cg::this_grid();
    __shared__ unsigned slds[NSEENW];   // 32 KB, reused by P3/P5/P10
    __shared__ int csum[16];
    __shared__ int rsum[16];
    const int tid  = threadIdx.x;
    const int gid  = blockIdx.x * TPB + tid;
    const int lane = tid & 63;

    // ---- P0: init first_idx + zero bitmap ----
    if (gid < N_LABELS) first_idx[gid] = INT_MAX;
    bitmap[gid] = 0u;                              // NWORDS == TOT
    __threadfence(); grid.sync();

    // ---- P1: blind seed over raster prefix ----
    if (gid < SEED_INT4) {
        int4 L = lab4[gid]; int b = gid * 4;
        atomicMin(&first_idx[L.x], b);
        atomicMin(&first_idx[L.y], b + 1);
        atomicMin(&first_idx[L.z], b + 2);
        atomicMin(&first_idx[L.w], b + 3);
    }
    __threadfence(); grid.sync();

    // ---- P2: seen snapshot 1 (full waves: N_LABELS % 64 == 0) ----
    if (gid < N_LABELS) {
        unsigned long long m = __ballot(first_idx[gid] != INT_MAX);
        if (lane == 0)       seen[gid >> 5] = (unsigned)m;
        else if (lane == 32) seen[gid >> 5] = (unsigned)(m >> 32);
    }
    __threadfence(); grid.sync();

    // ---- P3: pass A [SEED_INT4, A_END_INT4) ----
    {
        const uint4* s4 = (const uint4*)seen;
        uint4*       d4 = (uint4*)slds;
        for (int i = tid; i < NSEENW / 4; i += TPB) d4[i] = s4[i];
        __syncthreads();
        if (gid < A_END_INT4 - SEED_INT4) {
            int t = SEED_INT4 + gid;
            int4 L = lab4[t]; int b = t * 4;
            if (!((slds[L.x >> 5] >> (L.x & 31)) & 1u)) atomicMin(&first_idx[L.x], b);
            if (!((slds[L.y >> 5] >> (L.y & 31)) & 1u)) atomicMin(&first_idx[L.y], b + 1);
            if (!((slds[L.z >> 5] >> (L.z & 31)) & 1u)) atomicMin(&first_idx[L.z], b + 2);
            if (!((slds[L.w >> 5] >> (L.w & 31)) & 1u)) atomicMin(&first_idx[L.w], b + 3);
        }
    }
    __threadfence(); grid.sync();

    // ---- P4: seen snapshot 2 ----
    if (gid < N_LABELS) {
        unsigned long long m = __ballot(first_idx[gid] != INT_MAX);
        if (lane == 0)       seen[gid >> 5] = (unsigned)m;
        else if (lane == 32) seen[gid >> 5] = (unsigned)(m >> 32);
    }
    __threadfence(); grid.sync();

    // ---- P5: pass B [A_END_INT4, N_INT4) ----
    {
        __syncthreads();                    // slds quiescent before re-stage
        const uint4* s4 = (const uint4*)seen;
        uint4*       d4 = (uint4*)slds;
        for (int i = tid; i < NSEENW / 4; i += TPB) d4[i] = s4[i];
        __syncthreads();
        for (int t = A_END_INT4 + gid; t < N_INT4; t += TOT) {
            int4 L = lab4[t]; int b = t * 4;
            if (!((slds[L.x >> 5] >> (L.x & 31)) & 1u)) atomicMin(&first_idx[L.x], b);
            if (!((slds[L.y >> 5] >> (L.y & 31)) & 1u)) atomicMin(&first_idx[L.y], b + 1);
            if (!((slds[L.z >> 5] >> (L.z & 31)) & 1u)) atomicMin(&first_idx[L.z], b + 2);
            if (!((slds[L.w >> 5] >> (L.w & 31)) & 1u)) atomicMin(&first_idx[L.w], b + 3);
        }
    }
    __threadfence(); grid.sync();

    // ---- P6: scatter seed bits into occupancy bitmap ----
    if (gid < N_LABELS) {
        int fi = first_idx[gid];
        if (fi != INT_MAX) atomicOr(&bitmap[fi >> 5], 1u << (fi & 31));
    }
    __threadfence(); grid.sync();

    // ---- P7: per-chunk popcount sums (4 chunks/block) ----
    {
        int pc = __popc(bitmap[gid]);
        #pragma unroll
        for (int off = 32; off; off >>= 1) pc += __shfl_down(pc, off);
        if (lane == 0) csum[tid >> 6] = pc;
        __syncthreads();
        if (tid < 4)
            chunkSums[blockIdx.x * 4 + tid] =
                csum[tid * 4] + csum[tid * 4 + 1] + csum[tid * 4 + 2] + csum[tid * 4 + 3];
        __syncthreads();
    }
    __threadfence(); grid.sync();

    // ---- P8: chunk-prefix reduce + per-word exclusive prefix ----
    {
        int q = tid >> 8, subtid = tid & 255;
        int c = blockIdx.x * 4 + q;
        int acc = 0;
        for (int i = subtid; i < c; i += 256) acc += chunkSums[i];
        #pragma unroll
        for (int off = 32; off; off >>= 1) acc += __shfl_down(acc, off);
        if (lane == 0) rsum[tid >> 6] = acc;
        int pc = __popc(bitmap[gid]);
        int v = pc;
        #pragma unroll
        for (int off = 1; off < 64; off <<= 1) {
            int u = __shfl_up(v, off);
            if (lane >= off) v += u;
        }
        if (lane == 63) csum[tid >> 6] = v;
        __syncthreads();
        int chunkPref = rsum[4 * q] + rsum[4 * q + 1] + rsum[4 * q + 2] + rsum[4 * q + 3];
        int wq = (tid >> 6) & 3;
        int waveoff = 0;
        #pragma unroll
        for (int i = 0; i < 3; ++i) waveoff += (i < wq) ? csum[4 * q + i] : 0;
        wordPrefix[gid] = chunkPref + waveoff + v - pc;
        __syncthreads();
    }
    __threadfence(); grid.sync();

    // ---- P9: rank -> coin -> flip bit (ballot) ----
    if (gid < N_LABELS) {
        int fi = first_idx[gid];
        bool flip = false;
        if (fi != INT_MAX) {
            int w = fi >> 5;
            unsigned mask = (1u << (fi & 31)) - 1u;
            int rank = wordPrefix[w] + __popc(bitmap[w] & mask);
            flip = (coins[rank] >= 0.5f);
        }
        unsigned long long m = __ballot(flip);
        if (lane == 0)       flipbits[gid >> 5] = (unsigned)m;
        else if (lane == 32) flipbits[gid >> 5] = (unsigned)(m >> 32);
    }
    __threadfence(); grid.sync();

    // ---- P10: apply flips (LDS flip table, nt streams) ----
    {
        const uint4* s4 = (const uint4*)flipbits;
        uint4*       d4 = (uint4*)slds;
        for (int i = tid; i < NSEENW / 4; i += TPB) d4[i] = s4[i];
        __syncthreads();
        const f32x4* sp4  = (const f32x4*)spins;
        f32x4*       out4 = (f32x4*)out;
#define FLIP1(lbl, sv) __uint_as_float(__float_as_uint(sv) ^                   \
        ((((slds[(lbl) >> 5] >> ((lbl) & 31)) & 1u)) << 31))
        #pragma unroll
        for (int it = 0; it < 2; ++it) {
            int t0 = gid + it * 4 * TOT;
            int4  L0 = lab4[t0];
            int4  L1 = lab4[t0 + TOT];
            int4  L2 = lab4[t0 + 2 * TOT];
            int4  L3 = lab4[t0 + 3 * TOT];
            f32x4 s0 = __builtin_nontemporal_load(&sp4[t0]);
            f32x4 s1 = __builtin_nontemporal_load(&sp4[t0 + TOT]);
            f32x4 s2 = __builtin_nontemporal_load(&sp4[t0 + 2 * TOT]);
            f32x4 s3 = __builtin_nontemporal_load(&sp4[t0 + 3 * TOT]);
            f32x4 o0, o1, o2, o3;
            o0.x = FLIP1(L0.x, s0.x); o0.y = FLIP1(L0.y, s0.y);
            o0.z = FLIP1(L0.z, s0.z); o0.w = FLIP1(L0.w, s0.w);
            o1.x = FLIP1(L1.x, s1.x); o1.y = FLIP1(L1.y, s1.y);
            o1.z = FLIP1(L1.z, s1.z); o1.w = FLIP1(L1.w, s1.w);
            o2.x = FLIP1(L2.x, s2.x); o2.y = FLIP1(L2.y, s2.y);
            o2.z = FLIP1(L2.z, s2.z); o2.w = FLIP1(L2.w, s2.w);
            o3.x = FLIP1(L3.x, s3.x); o3.y = FLIP1(L3.y, s3.y);
            o3.z = FLIP1(L3.z, s3.z); o3.w = FLIP1(L3.w, s3.w);
            __builtin_nontemporal_store(o0, &out4[t0]);
            __builtin_nontemporal_store(o1, &out4[t0 + TOT]);
            __builtin_nontemporal_store(o2, &out4[t0 + 2 * TOT]);
            __builtin_nontemporal_store(o3, &out4[t0 + 3 * TOT]);
        }
#undef FLIP1
    }
}

// ================= FALLBACK: the proven R20 11-kernel path =================
__global__ void k_init(int* __restrict__ first_idx) {
    int t = blockIdx.x * blockDim.x + threadIdx.x;
    first_idx[t] = INT_MAX;
}

__global__ void k_seed_blind(const int4* __restrict__ lab4, int* __restrict__ first_idx,
                             uint4* __restrict__ bitmap4) {
    if (blockIdx.x < SEED_BLOCKS) {
        int t = blockIdx.x * blockDim.x + threadIdx.x;
        int4 L = lab4[t];
        int b  = t * 4;
        atomicMin(&first_idx[L.x], b);
        atomicMin(&first_idx[L.y], b + 1);
        atomicMin(&first_idx[L.z], b + 2);
        atomicMin(&first_idx[L.w], b + 3);
    } else {
        int i = (blockIdx.x - SEED_BLOCKS) * blockDim.x + threadIdx.x;
        bitmap4[i] = make_uint4(0u, 0u, 0u, 0u);
    }
}

__global__ void k_seen(const int* __restrict__ first_idx, unsigned* __restrict__ seen) {
    int l = blockIdx.x * blockDim.x + threadIdx.x;
    unsigned long long m = __ballot(first_idx[l] != INT_MAX);
    int lane = threadIdx.x & 63;
    if (lane == 0)       seen[l >> 5] = (unsigned)m;
    else if (lane == 32) seen[l >> 5] = (unsigned)(m >> 32);
}

__global__ void __launch_bounds__(FLAT_TPB)
k_complete(const int4* __restrict__ lab4, int* __restrict__ first_idx,
           const unsigned* __restrict__ seen, int start4, int end4) {
    __shared__ unsigned slds[NSEENW];
    {
        const uint4* s4 = (const uint4*)seen;
        uint4*       d4 = (uint4*)slds;
        for (int i = threadIdx.x; i < NSEENW / 4; i += blockDim.x) d4[i] = s4[i];
    }
    __syncthreads();
    const int stride = FLAT_BLOCKS * FLAT_TPB;
    for (int t = start4 + blockIdx.x * blockDim.x + threadIdx.x; t < end4; t += stride) {
        int4 L = lab4[t];
        int b  = t * 4;
        if (!((slds[L.x >> 5] >> (L.x & 31)) & 1u)) atomicMin(&first_idx[L.x], b);
        if (!((slds[L.y >> 5] >> (L.y & 31)) & 1u)) atomicMin(&first_idx[L.y], b + 1);
        if (!((slds[L.z >> 5] >> (L.z & 31)) & 1u)) atomicMin(&first_idx[L.z], b + 2);
        if (!((slds[L.w >> 5] >> (L.w & 31)) & 1u)) atomicMin(&first_idx[L.w], b + 3);
    }
}

__global__ void k_scatter(const int* __restrict__ first_idx, unsigned* __restrict__ bitmap) {
    int l = blockIdx.x * blockDim.x + threadIdx.x;
    if (l >= N_LABELS) return;
    int fi = first_idx[l];
    if (fi != INT_MAX) atomicOr(&bitmap[fi >> 5], 1u << (fi & 31));
}

__global__ void k_chunk_sums(const unsigned* __restrict__ bitmap, int* __restrict__ chunkSums) {
    __shared__ int waveSums[4];
    int w  = blockIdx.x * WPC + threadIdx.x;
    int pc = __popc(bitmap[w]);
    #pragma unroll
    for (int off = 32; off; off >>= 1) pc += __shfl_down(pc, off);
    if ((threadIdx.x & 63) == 0) waveSums[threadIdx.x >> 6] = pc;
    __syncthreads();
    if (threadIdx.x == 0)
        chunkSums[blockIdx.x] = waveSums[0] + waveSums[1] + waveSums[2] + waveSums[3];
}

__global__ void k_word_prefix(const unsigned* __restrict__ bitmap,
                              const int* __restrict__ chunkSums,
                              int* __restrict__ wordPrefix) {
    __shared__ int wsum[4];
    __shared__ int rsum2[4];
    int tid = threadIdx.x, lane = tid & 63, wid = tid >> 6;
    int b = blockIdx.x;
    int acc = 0;
    for (int i = tid; i < b; i += WPC) acc += chunkSums[i];
    #pragma unroll
    for (int off = 32; off; off >>= 1) acc += __shfl_down(acc, off);
    if (lane == 0) rsum2[wid] = acc;
    int w  = b * WPC + tid;
    int pc = __popc(bitmap[w]);
    int v = pc;
    #pragma unroll
    for (int off = 1; off < 64; off <<= 1) {
        int u = __shfl_up(v, off);
        if (lane >= off) v += u;
    }
    if (lane == 63) wsum[wid] = v;
    __syncthreads();
    int chunkPref = rsum2[0] + rsum2[1] + rsum2[2] + rsum2[3];
    int waveoff = 0;
    #pragma unroll
    for (int i = 0; i < 4; ++i) waveoff += (i < wid) ? wsum[i] : 0;
    wordPrefix[w] = chunkPref + waveoff + v - pc;
}

__global__ void k_rank_flip(const int* __restrict__ first_idx,
                            const unsigned* __restrict__ bitmap,
                            const int* __restrict__ wordPrefix,
                            const float* __restrict__ coins,
                            unsigned* __restrict__ flipbits) {
    int l = blockIdx.x * blockDim.x + threadIdx.x;
    int fi = first_idx[l];
    bool flip = false;
    if (fi != INT_MAX) {
        int w = fi >> 5;
        unsigned mask = (1u << (fi & 31)) - 1u;
        int rank = wordPrefix[w] + __popc(bitmap[w] & mask);
        flip = (coins[rank] >= 0.5f);
    }
    unsigned long long m = __ballot(flip);
    int lane = threadIdx.x & 63;
    if (lane == 0)       flipbits[l >> 5] = (unsigned)m;
    else if (lane == 32) flipbits[l >> 5] = (unsigned)(m >> 32);
}

__global__ void __launch_bounds__(FLAT_TPB)
k_out(const int4* __restrict__ lab4, const float* __restrict__ spins,
      const unsigned* __restrict__ flipbits, float* __restrict__ out) {
    __shared__ unsigned flds[NSEENW];
    {
        const uint4* s4 = (const uint4*)flipbits;
        uint4*       d4 = (uint4*)flds;
        for (int i = threadIdx.x; i < NSEENW / 4; i += blockDim.x) d4[i] = s4[i];
    }
    __syncthreads();
    const f32x4* sp4  = (const f32x4*)spins;
    f32x4*       out4 = (f32x4*)out;
    int base = blockIdx.x * blockDim.x + threadIdx.x;
#define FLIP1(lbl, sv) __uint_as_float(__float_as_uint(sv) ^                   \
        ((((flds[(lbl) >> 5] >> ((lbl) & 31)) & 1u)) << 31))
    #pragma unroll
    for (int it = 0; it < 2; ++it) {
        int t0 = base + it * 4 * FLAT_THREADS;
        int4  L0 = lab4[t0];
        int4  L1 = lab4[t0 + FLAT_THREADS];
        int4  L2 = lab4[t0 + 2 * FLAT_THREADS];
        int4  L3 = lab4[t0 + 3 * FLAT_THREADS];
        f32x4 s0 = __builtin_nontemporal_load(&sp4[t0]);
        f32x4 s1 = __builtin_nontemporal_load(&sp4[t0 + FLAT_THREADS]);
        f32x4 s2 = __builtin_nontemporal_load(&sp4[t0 + 2 * FLAT_THREADS]);
        f32x4 s3 = __builtin_nontemporal_load(&sp4[t0 + 3 * FLAT_THREADS]);
        f32x4 o0, o1, o2, o3;
        o0.x = FLIP1(L0.x, s0.x); o0.y = FLIP1(L0.y, s0.y);
        o0.z = FLIP1(L0.z, s0.z); o0.w = FLIP1(L0.w, s0.w);
        o1.x = FLIP1(L1.x, s1.x); o1.y = FLIP1(L1.y, s1.y);
        o1.z = FLIP1(L1.z, s1.z); o1.w = FLIP1(L1.w, s1.w);
        o2.x = FLIP1(L2.x, s2.x); o2.y = FLIP1(L2.y, s2.y);
        o2.z = FLIP1(L2.z, s2.z); o2.w = FLIP1(L2.w, s2.w);
        o3.x = FLIP1(L3.x, s3.x); o3.y = FLIP1(L3.y, s3.y);
        o3.z = FLIP1(L3.z, s3.z); o3.w = FLIP1(L3.w, s3.w);
        __builtin_nontemporal_store(o0, &out4[t0]);
        __builtin_nontemporal_store(o1, &out4[t0 + FLAT_THREADS]);
        __builtin_nontemporal_store(o2, &out4[t0 + 2 * FLAT_THREADS]);
        __builtin_nontemporal_store(o3, &out4[t0 + 3 * FLAT_THREADS]);
    }
#undef FLIP1
}

extern "C" void kernel_launch(void* const* d_in, const int* in_sizes, int n_in,
                              void* d_out, int out_size, void* d_ws, size_t ws_size,
                              hipStream_t stream) {
    const float* spins  = (const float*)d_in[0];
    const int*   labels = (const int*)d_in[1];
    const float* coins  = (const float*)d_in[2];
    float*       out    = (float*)d_out;

    // workspace layout (~5.2 MB total)
    char* ws = (char*)d_ws;
    int*      first_idx  = (int*)ws;                                   // 1 MB
    unsigned* bitmap     = (unsigned*)(ws + (1u << 20));               // 2 MB
    int*      wordPrefix = (int*)(ws + 3u * (1u << 20));               // 2 MB
    int*      chunkSums  = (int*)(ws + 5u * (1u << 20));               // 8 KB
    unsigned* seen       = (unsigned*)(ws + 5u*(1u<<20) + (1u<<15));   // 32 KB
    unsigned* flipbits   = (unsigned*)(ws + 5u*(1u<<20) + 2u*(1u<<15)); // 32 KB

    // Try the fused cooperative kernel (removes ~10 launch gaps).
    const int4* lab4 = (const int4*)labels;
    void* args[] = { (void*)&lab4, (void*)&first_idx, (void*)&bitmap, (void*)&seen,
                     (void*)&flipbits, (void*)&chunkSums, (void*)&wordPrefix,
                     (void*)&coins, (void*)&spins, (void*)&out };
    hipError_t e = hipLaunchCooperativeKernel(k_mega, dim3(GRID), dim3(TPB),
                                              args, 0u, stream);
    if (e == hipSuccess) return;
    (void)hipGetLastError();   // clear error; fall back to the proven 11-kernel path

    k_init<<<N_LABELS / 256, 256, 0, stream>>>(first_idx);
    k_seed_blind<<<SEED_BLOCKS + ZERO_BLOCKS, SEED_TPB, 0, stream>>>(
        (const int4*)labels, first_idx, (uint4*)bitmap);
    k_seen<<<N_LABELS / 256, 256, 0, stream>>>(first_idx, seen);
    k_complete<<<FLAT_BLOCKS, FLAT_TPB, 0, stream>>>(
        (const int4*)labels, first_idx, seen, SEED_INT4, A_END_INT4);
    k_seen<<<N_LABELS / 256, 256, 0, stream>>>(first_idx, seen);
    k_complete<<<FLAT_BLOCKS, FLAT_TPB, 0, stream>>>(
        (const int4*)labels, first_idx, seen, A_END_INT4, N_INT4);
    k_scatter<<<N_LABELS / 256, 256, 0, stream>>>(first_idx, bitmap);
    k_chunk_sums<<<NCHUNKS, WPC, 0, stream>>>(bitmap, chunkSums);
    k_word_prefix<<<NCHUNKS, WPC, 0, stream>>>(bitmap, chunkSums, wordPrefix);
    k_rank_flip<<<N_LABELS / 256, 256, 0, stream>>>(first_idx, bitmap, wordPrefix, coins, flipbits);
    k_out<<<FLAT_BLOCKS, FLAT_TPB, 0, stream>>>((const int4*)labels, (const float*)spins,
                                                flipbits, (float*)out);
}

// Round 22
// 113.632 us; speedup vs baseline: 15.8662x; 15.8662x over previous
//
#include <hip/hip_runtime.h>
#include <limits.h>

// Problem constants (fixed by the reference: LATTICE=(4096,4096), N_CLUSTERS=262144)
#define N_SITES   (4096 * 4096)      // 16,777,216
#define N_INT4    (N_SITES / 4)      // 4,194,304
#define N_LABELS  262144
#define NWORDS    (N_SITES / 32)     // 524,288 bitmap words
#define NSEENW    (N_LABELS / 32)    // 8,192 seen/flip bitmap words (32 KB)
#define WPC       256                // words per chunk
#define NCHUNKS   (NWORDS / WPC)     // 2048

// Completion strategy (R15-R20 lessons, settled):
//  - blind fire-and-forget atomicMin (commutative -> exact; no dependent
//    global reads of the live table in any streaming loop)
//  - gate only on an LDS seen-bitmap snapshot, re-snapshotted at a kernel
//    boundary so pass B fires ~0 atomics
//  - atomic ledger (~40ns/atomic): S=524K, A=1.05M sites minimizes
//    S + A*e^(-S/256K) + B*e^(-(S+A)/256K)  ~ 692K atomics
//  - R21 lesson: cooperative grid.sync costs ~150us each on 8-XCD MI355X;
//    11 stream-ordered launches (~1.5us/gap) are 10x cheaper. Keep kernels.
#define SEED_TPB    256
#define SEED_BLOCKS 512
#define SEED_INT4   (SEED_BLOCKS * SEED_TPB)     // 131,072 int4 = 524,288 sites
#define ZERO_BLOCKS 512                          // zero the 2 MB bitmap
#define A_END_INT4  (SEED_INT4 + 262144)         // 393,216 int4 = 1,572,864 sites

// Flat passes: persistent geometry. 512 blocks x 1024 thr, 32 KB LDS staged once.
#define FLAT_BLOCKS 512
#define FLAT_TPB    1024
#define FLAT_THREADS (FLAT_BLOCKS * FLAT_TPB)   // 524,288

// plain ext-vector type for nontemporal builtins (HIP_vector_type is rejected)
typedef float f32x4 __attribute__((ext_vector_type(4)));

// ---------------- kernel 1: init first_idx ----------------
__global__ void k_init(int* __restrict__ first_idx) {
    int t = blockIdx.x * blockDim.x + threadIdx.x;   // N_LABELS threads
    first_idx[t] = INT_MAX;
}

// ---------------- kernel 2a: blind seed + bitmap zero ----------------
__global__ void k_seed_blind(const int4* __restrict__ lab4, int* __restrict__ first_idx,
                             uint4* __restrict__ bitmap4) {
    if (blockIdx.x < SEED_BLOCKS) {
        int t = blockIdx.x * blockDim.x + threadIdx.x;   // [0, SEED_INT4)
        int4 L = lab4[t];
        int b  = t * 4;
        atomicMin(&first_idx[L.x], b);
        atomicMin(&first_idx[L.y], b + 1);
        atomicMin(&first_idx[L.z], b + 2);
        atomicMin(&first_idx[L.w], b + 3);
    } else {
        int i = (blockIdx.x - SEED_BLOCKS) * blockDim.x + threadIdx.x;
        bitmap4[i] = make_uint4(0u, 0u, 0u, 0u);   // 131,072 uint4
    }
}

// ---------------- kernel 2b: build 32 KB 'seen' bitmap from first_idx ----------------
// Run after seed (snapshot 1) and again after pass A (snapshot 2).
__global__ void k_seen(const int* __restrict__ first_idx, unsigned* __restrict__ seen) {
    int l = blockIdx.x * blockDim.x + threadIdx.x;       // N_LABELS threads
    unsigned long long m = __ballot(first_idx[l] != INT_MAX);
    int lane = threadIdx.x & 63;
    if (lane == 0)       seen[l >> 5] = (unsigned)m;
    else if (lane == 32) seen[l >> 5] = (unsigned)(m >> 32);
}

// ---------------- kernel 2c: completion pass over [start4, end4) ----------------
// LDS seen-probe; unseen -> BLIND fire-and-forget atomicMin (no dependent
// global loads in the loop). Exactness: the covered range at snapshot time is
// a raster PREFIX, so seen => first_idx final; unseen => blind min is exact.
__global__ void __launch_bounds__(FLAT_TPB)
k_complete(const int4* __restrict__ lab4, int* __restrict__ first_idx,
           const unsigned* __restrict__ seen, int start4, int end4) {
    __shared__ unsigned slds[NSEENW];
    {
        const uint4* s4 = (const uint4*)seen;
        uint4*       d4 = (uint4*)slds;
        for (int i = threadIdx.x; i < NSEENW / 4; i += blockDim.x) d4[i] = s4[i];
    }
    __syncthreads();
    const int stride = FLAT_BLOCKS * FLAT_TPB;
    for (int t = start4 + blockIdx.x * blockDim.x + threadIdx.x; t < end4; t += stride) {
        int4 L = lab4[t];
        int b  = t * 4;
        if (!((slds[L.x >> 5] >> (L.x & 31)) & 1u)) atomicMin(&first_idx[L.x], b);
        if (!((slds[L.y >> 5] >> (L.y & 31)) & 1u)) atomicMin(&first_idx[L.y], b + 1);
        if (!((slds[L.z >> 5] >> (L.z & 31)) & 1u)) atomicMin(&first_idx[L.z], b + 2);
        if (!((slds[L.w >> 5] >> (L.w & 31)) & 1u)) atomicMin(&first_idx[L.w], b + 3);
    }
}

// ---------------- kernel 3: scatter seed bits into occupancy bitmap ----------------
__global__ void k_scatter(const int* __restrict__ first_idx, unsigned* __restrict__ bitmap) {
    int l = blockIdx.x * blockDim.x + threadIdx.x;
    if (l >= N_LABELS) return;
    int fi = first_idx[l];
    if (fi != INT_MAX) atomicOr(&bitmap[fi >> 5], 1u << (fi & 31));
}

// ---------------- kernel 4: per-chunk popcount sums ----------------
__global__ void k_chunk_sums(const unsigned* __restrict__ bitmap, int* __restrict__ chunkSums) {
    __shared__ int waveSums[4];
    int w  = blockIdx.x * WPC + threadIdx.x;
    int pc = __popc(bitmap[w]);
    #pragma unroll
    for (int off = 32; off; off >>= 1) pc += __shfl_down(pc, off);
    if ((threadIdx.x & 63) == 0) waveSums[threadIdx.x >> 6] = pc;
    __syncthreads();
    if (threadIdx.x == 0)
        chunkSums[blockIdx.x] = waveSums[0] + waveSums[1] + waveSums[2] + waveSums[3];
}

// ---------------- kernel 5: fused chunk-prefix reduce + per-word prefix ----------------
__global__ void k_word_prefix(const unsigned* __restrict__ bitmap,
                              const int* __restrict__ chunkSums,
                              int* __restrict__ wordPrefix) {
    __shared__ int wsum[4];
    __shared__ int rsum[4];
    int tid = threadIdx.x, lane = tid & 63, wid = tid >> 6;
    int b = blockIdx.x;
    // chunk prefix: block-reduce chunkSums[0..b)
    int acc = 0;
    for (int i = tid; i < b; i += WPC) acc += chunkSums[i];
    #pragma unroll
    for (int off = 32; off; off >>= 1) acc += __shfl_down(acc, off);
    if (lane == 0) rsum[wid] = acc;
    // per-word popcount scan
    int w  = b * WPC + tid;
    int pc = __popc(bitmap[w]);
    int v = pc;
    #pragma unroll
    for (int off = 1; off < 64; off <<= 1) {
        int u = __shfl_up(v, off);
        if (lane >= off) v += u;
    }
    if (lane == 63) wsum[wid] = v;
    __syncthreads();
    int chunkPref = rsum[0] + rsum[1] + rsum[2] + rsum[3];
    int waveoff = 0;
    #pragma unroll
    for (int i = 0; i < 4; ++i) waveoff += (i < wid) ? wsum[i] : 0;
    wordPrefix[w] = chunkPref + waveoff + v - pc;  // global exclusive prefix
}

// ---------------- kernel 6: rank -> coin -> flip bit (ballot, NO atomics) ----------------
__global__ void k_rank_flip(const int* __restrict__ first_idx,
                            const unsigned* __restrict__ bitmap,
                            const int* __restrict__ wordPrefix,
                            const float* __restrict__ coins,
                            unsigned* __restrict__ flipbits) {
    int l = blockIdx.x * blockDim.x + threadIdx.x;   // N_LABELS threads
    int fi = first_idx[l];
    bool flip = false;
    if (fi != INT_MAX) {
        int w = fi >> 5;
        unsigned mask = (1u << (fi & 31)) - 1u;
        int rank = wordPrefix[w] + __popc(bitmap[w] & mask);
        flip = (coins[rank] >= 0.5f);
    }
    unsigned long long m = __ballot(flip);
    int lane = threadIdx.x & 63;
    if (lane == 0)       flipbits[l >> 5] = (unsigned)m;
    else if (lane == 32) flipbits[l >> 5] = (unsigned)(m >> 32);
}

// ---------------- kernel 7: apply flips (persistent, LDS table, nt streams) ----------------
__global__ void __launch_bounds__(FLAT_TPB)
k_out(const int4* __restrict__ lab4, const float* __restrict__ spins,
      const unsigned* __restrict__ flipbits, float* __restrict__ out) {
    __shared__ unsigned flds[NSEENW];
    {
        const uint4* s4 = (const uint4*)flipbits;
        uint4*       d4 = (uint4*)flds;
        for (int i = threadIdx.x; i < NSEENW / 4; i += blockDim.x) d4[i] = s4[i];
    }
    __syncthreads();
    const f32x4* sp4  = (const f32x4*)spins;
    f32x4*       out4 = (f32x4*)out;
    int base = blockIdx.x * blockDim.x + threadIdx.x;
#define FLIP1(lbl, sv) __uint_as_float(__float_as_uint(sv) ^                   \
        ((((flds[(lbl) >> 5] >> ((lbl) & 31)) & 1u)) << 31))
    #pragma unroll
    for (int it = 0; it < 2; ++it) {
        int t0 = base + it * 4 * FLAT_THREADS;
        int4  L0 = lab4[t0];
        int4  L1 = lab4[t0 + FLAT_THREADS];
        int4  L2 = lab4[t0 + 2 * FLAT_THREADS];
        int4  L3 = lab4[t0 + 3 * FLAT_THREADS];
        f32x4 s0 = __builtin_nontemporal_load(&sp4[t0]);
        f32x4 s1 = __builtin_nontemporal_load(&sp4[t0 + FLAT_THREADS]);
        f32x4 s2 = __builtin_nontemporal_load(&sp4[t0 + 2 * FLAT_THREADS]);
        f32x4 s3 = __builtin_nontemporal_load(&sp4[t0 + 3 * FLAT_THREADS]);
        f32x4 o0, o1, o2, o3;
        o0.x = FLIP1(L0.x, s0.x); o0.y = FLIP1(L0.y, s0.y);
        o0.z = FLIP1(L0.z, s0.z); o0.w = FLIP1(L0.w, s0.w);
        o1.x = FLIP1(L1.x, s1.x); o1.y = FLIP1(L1.y, s1.y);
        o1.z = FLIP1(L1.z, s1.z); o1.w = FLIP1(L1.w, s1.w);
        o2.x = FLIP1(L2.x, s2.x); o2.y = FLIP1(L2.y, s2.y);
        o2.z = FLIP1(L2.z, s2.z); o2.w = FLIP1(L2.w, s2.w);
        o3.x = FLIP1(L3.x, s3.x); o3.y = FLIP1(L3.y, s3.y);
        o3.z = FLIP1(L3.z, s3.z); o3.w = FLIP1(L3.w, s3.w);
        __builtin_nontemporal_store(o0, &out4[t0]);
        __builtin_nontemporal_store(o1, &out4[t0 + FLAT_THREADS]);
        __builtin_nontemporal_store(o2, &out4[t0 + 2 * FLAT_THREADS]);
        __builtin_nontemporal_store(o3, &out4[t0 + 3 * FLAT_THREADS]);
    }
#undef FLIP1
}

extern "C" void kernel_launch(void* const* d_in, const int* in_sizes, int n_in,
                              void* d_out, int out_size, void* d_ws, size_t ws_size,
                              hipStream_t stream) {
    const float* spins  = (const float*)d_in[0];
    const int*   labels = (const int*)d_in[1];
    const float* coins  = (const float*)d_in[2];
    float*       out    = (float*)d_out;

    // workspace layout (~5.2 MB total)
    char* ws = (char*)d_ws;
    int*      first_idx  = (int*)ws;                                   // 1 MB
    unsigned* bitmap     = (unsigned*)(ws + (1u << 20));               // 2 MB
    int*      wordPrefix = (int*)(ws + 3u * (1u << 20));               // 2 MB
    int*      chunkSums  = (int*)(ws + 5u * (1u << 20));               // 8 KB
    unsigned* seen       = (unsigned*)(ws + 5u*(1u<<20) + (1u<<15));   // 32 KB
    unsigned* flipbits   = (unsigned*)(ws + 5u*(1u<<20) + 2u*(1u<<15)); // 32 KB

    k_init<<<N_LABELS / 256, 256, 0, stream>>>(first_idx);
    k_seed_blind<<<SEED_BLOCKS + ZERO_BLOCKS, SEED_TPB, 0, stream>>>(
        (const int4*)labels, first_idx, (uint4*)bitmap);
    k_seen<<<N_LABELS / 256, 256, 0, stream>>>(first_idx, seen);
    k_complete<<<FLAT_BLOCKS, FLAT_TPB, 0, stream>>>(
        (const int4*)labels, first_idx, seen, SEED_INT4, A_END_INT4);   // pass A
    k_seen<<<N_LABELS / 256, 256, 0, stream>>>(first_idx, seen);        // re-snapshot
    k_complete<<<FLAT_BLOCKS, FLAT_TPB, 0, stream>>>(
        (const int4*)labels, first_idx, seen, A_END_INT4, N_INT4);      // pass B
    k_scatter<<<N_LABELS / 256, 256, 0, stream>>>(first_idx, bitmap);
    k_chunk_sums<<<NCHUNKS, WPC, 0, stream>>>(bitmap, chunkSums);
    k_word_prefix<<<NCHUNKS, WPC, 0, stream>>>(bitmap, chunkSums, wordPrefix);
    k_rank_flip<<<N_LABELS / 256, 256, 0, stream>>>(first_idx, bitmap, wordPrefix, coins, flipbits);
    k_out<<<FLAT_BLOCKS, FLAT_TPB, 0, stream>>>((const int4*)labels, (const float*)spins,
                                                flipbits, (float*)out);
}